// Round 2
// baseline (62.522 us; speedup 1.0000x reference)
//
#include <hip/hip_runtime.h>
#include <math.h>

#define NROWS_MAX 2000
#define D 8
#define H 16
#define HD 128

__device__ __forceinline__ float sigmoidf(float x) {
    return 1.0f / (1.0f + expf(-x));
}

__global__ __launch_bounds__(256) void vdlv_kernel(
    const float* __restrict__ q_mu,
    const float* __restrict__ q_dim_v,
    const float* __restrict__ q_dim_B,
    const float* __restrict__ q_time_var,
    const float* __restrict__ eps,
    float* __restrict__ out,
    int n_rows)
{
    int gid = blockIdx.x * blockDim.x + threadIdx.x;
    if (gid >= n_rows * H) return;
    int n = gid >> 4;   // row
    int h = gid & 15;   // horizon slot

    // Shared small parameters (broadcast loads, L1/L2 cached)
    float c = sigmoidf(q_dim_v[0]);
    float t[D];
#pragma unroll
    for (int i = 0; i < D; ++i) t[i] = 2.0f * sigmoidf(q_dim_B[i]) - 1.0f;
    float s = sigmoidf(q_time_var[n]);

    // Build M = s*(t t^T + c*11^T) + 1e-6 I (lower triangle), Cholesky in place.
    // All indices compile-time after unroll -> stays in registers.
    float L[D][D];
#pragma unroll
    for (int i = 0; i < D; ++i) {
#pragma unroll
        for (int j = 0; j <= i; ++j) {
            L[i][j] = s * (t[i] * t[j] + c) + ((i == j) ? 1e-6f : 0.0f);
        }
    }

#pragma unroll
    for (int k = 0; k < D; ++k) {
        float d = L[k][k];
#pragma unroll
        for (int m = 0; m < k; ++m) d -= L[k][m] * L[k][m];
        d = sqrtf(d);
        L[k][k] = d;
        float inv = 1.0f / d;
#pragma unroll
        for (int i = k + 1; i < D; ++i) {
            float v = L[i][k];
#pragma unroll
            for (int m = 0; m < k; ++m) v -= L[i][m] * L[k][m];
            L[i][k] = v * inv;
        }
    }

    // out[n, i*H + h] = q_mu[n, i*H + h] + sum_{j<=i} L[i][j] * eps[n, j*H + h]
    const float* __restrict__ erow = eps  + (size_t)n * HD + h;
    const float* __restrict__ mrow = q_mu + (size_t)n * HD + h;
    float* __restrict__ orow       = out  + (size_t)n * HD + h;

    float e[D];
#pragma unroll
    for (int j = 0; j < D; ++j) e[j] = erow[j * H];

#pragma unroll
    for (int i = 0; i < D; ++i) {
        float acc = mrow[i * H];
#pragma unroll
        for (int j = 0; j <= i; ++j) acc = fmaf(L[i][j], e[j], acc);
        orow[i * H] = acc;
    }
}

extern "C" void kernel_launch(void* const* d_in, const int* in_sizes, int n_in,
                              void* d_out, int out_size, void* d_ws, size_t ws_size,
                              hipStream_t stream) {
    const float* q_mu       = (const float*)d_in[0];
    const float* q_dim_v    = (const float*)d_in[1];
    const float* q_dim_B    = (const float*)d_in[2];
    const float* q_time_var = (const float*)d_in[3];
    const float* eps        = (const float*)d_in[4];
    float* out              = (float*)d_out;

    int n_rows = in_sizes[3];           // N from q_time_var
    int total  = n_rows * H;            // one thread per (n, h)
    int block  = 256;
    int grid   = (total + block - 1) / block;

    vdlv_kernel<<<grid, block, 0, stream>>>(q_mu, q_dim_v, q_dim_B, q_time_var,
                                            eps, out, n_rows);
}